// Round 1
// baseline (495.313 us; speedup 1.0000x reference)
//
#include <hip/hip_runtime.h>

#define SEQ   550
#define MID   100
#define EMBED 10
#define NROW  300   // 3*MID
#define TPB   320
#define ESTR  12    // seq_emb row stride (floats), 48B = float4-aligned

__device__ __forceinline__ float fast_sigmoid(float x) {
    return 1.0f / (1.0f + __expf(-x));
}
// tanh(x) = 1 - 2/(exp(2x)+1); saturates correctly at +/-inf in fp32
__device__ __forceinline__ float fast_tanh(float x) {
    return 1.0f - 2.0f / (__expf(2.0f * x) + 1.0f);
}

__global__ __launch_bounds__(TPB) void gru_fused(
    const int*   __restrict__ x,
    const float* __restrict__ hidden,
    const float* __restrict__ embed,
    const float* __restrict__ w_ih,
    const float* __restrict__ w_hh,
    const float* __restrict__ b_ih,
    const float* __restrict__ b_hh,
    const float* __restrict__ fc_w,
    const float* __restrict__ fc_b,
    float*       __restrict__ out)
{
    // LDS: embedded sequence (gather hoisted out of the scan), h, gate scratch
    __shared__ __align__(16) float seq_emb[SEQ * ESTR];   // 26400 B
    __shared__ __align__(16) float h_lds[128];            // h[0:100] + zero pad
    __shared__ float a_r[MID], a_z[MID], g_in[MID], g_hn[MID];
    __shared__ float partial[MID];

    const int tid = threadIdx.x;

    // ---- staging: seq_emb[t][k] = embed_table[x[t]][k] ----
    for (int i = tid; i < SEQ * EMBED; i += TPB) {
        int t = i / EMBED;
        int k = i - t * EMBED;
        seq_emb[t * ESTR + k] = embed[x[t] * EMBED + k];
    }
    if (tid < 128) h_lds[tid] = (tid < MID) ? hidden[tid] : 0.0f;

    // ---- per-thread weight row in registers ----
    float4 whh[25];          // w_hh[row][0:100] : 100 VGPRs
    float  wih[EMBED];
    float  bih = 0.0f, bhh = 0.0f;
    if (tid < NROW) {
        const float4* wr = (const float4*)(w_hh + tid * MID);  // 400B offset: 16B aligned
        #pragma unroll
        for (int k = 0; k < 25; k++) whh[k] = wr[k];
        #pragma unroll
        for (int k = 0; k < EMBED; k++) wih[k] = w_ih[tid * EMBED + k];
        bih = b_ih[tid];
        bhh = b_hh[tid];
    }
    const int g = tid / MID;       // 0 = r-gate, 1 = z-gate, 2 = n-gate
    const int j = tid - g * MID;   // hidden unit index

    __syncthreads();

    #pragma unroll 1
    for (int t = 0; t < SEQ; t++) {
        // ---- phase 1: per-row gate projections ----
        if (tid < NROW) {
            const float4* ev = (const float4*)(seq_emb + t * ESTR);
            float4 e0 = ev[0], e1 = ev[1], e2 = ev[2];   // broadcast reads
            float gi = bih;
            gi += wih[0]*e0.x; gi += wih[1]*e0.y; gi += wih[2]*e0.z; gi += wih[3]*e0.w;
            gi += wih[4]*e1.x; gi += wih[5]*e1.y; gi += wih[6]*e1.z; gi += wih[7]*e1.w;
            gi += wih[8]*e2.x; gi += wih[9]*e2.y;

            const float4* h4 = (const float4*)h_lds;
            float a0 = bhh, a1 = 0.0f, a2 = 0.0f, a3 = 0.0f;
            #pragma unroll
            for (int k = 0; k < 24; k += 4) {
                float4 w0 = whh[k],   hv0 = h4[k];
                float4 w1 = whh[k+1], hv1 = h4[k+1];
                float4 w2 = whh[k+2], hv2 = h4[k+2];
                float4 w3 = whh[k+3], hv3 = h4[k+3];
                a0 += w0.x*hv0.x; a0 += w0.y*hv0.y; a0 += w0.z*hv0.z; a0 += w0.w*hv0.w;
                a1 += w1.x*hv1.x; a1 += w1.y*hv1.y; a1 += w1.z*hv1.z; a1 += w1.w*hv1.w;
                a2 += w2.x*hv2.x; a2 += w2.y*hv2.y; a2 += w2.z*hv2.z; a2 += w2.w*hv2.w;
                a3 += w3.x*hv3.x; a3 += w3.y*hv3.y; a3 += w3.z*hv3.z; a3 += w3.w*hv3.w;
            }
            {
                float4 w0 = whh[24], hv0 = h4[24];
                a0 += w0.x*hv0.x; a1 += w0.y*hv0.y; a2 += w0.z*hv0.z; a3 += w0.w*hv0.w;
            }
            float gh = (a0 + a1) + (a2 + a3);

            if (g == 0)      a_r[j] = gi + gh;
            else if (g == 1) a_z[j] = gi + gh;
            else             { g_in[j] = gi; g_hn[j] = gh; }
        }
        __syncthreads();

        // ---- phase 2: gate mixing + h update (threads 0..99) ----
        if (tid < MID) {
            float r = fast_sigmoid(a_r[tid]);
            float z = fast_sigmoid(a_z[tid]);
            float n = fast_tanh(g_in[tid] + r * g_hn[tid]);
            float hprev = h_lds[tid];
            h_lds[tid] = n + z * (hprev - n);   // (1-z)*n + z*h
        }
        __syncthreads();
    }

    // ---- epilogue: out = sigmoid(relu(h) . fc_w + fc_b) ----
    if (tid < MID) partial[tid] = fmaxf(h_lds[tid], 0.0f) * fc_w[tid];
    __syncthreads();
    if (tid == 0) {
        float s = fc_b[0];
        #pragma unroll 1
        for (int k = 0; k < MID; k++) s += partial[k];
        out[0] = fast_sigmoid(s);
    }
}

extern "C" void kernel_launch(void* const* d_in, const int* in_sizes, int n_in,
                              void* d_out, int out_size, void* d_ws, size_t ws_size,
                              hipStream_t stream) {
    const int*   x      = (const int*)  d_in[0];
    const float* hidden = (const float*)d_in[1];
    const float* embed  = (const float*)d_in[2];
    const float* w_ih   = (const float*)d_in[3];
    const float* w_hh   = (const float*)d_in[4];
    const float* b_ih   = (const float*)d_in[5];
    const float* b_hh   = (const float*)d_in[6];
    const float* fc_w   = (const float*)d_in[7];
    const float* fc_b   = (const float*)d_in[8];
    float*       out    = (float*)d_out;

    gru_fused<<<1, TPB, 0, stream>>>(x, hidden, embed, w_ih, w_hh,
                                     b_ih, b_hh, fc_w, fc_b, out);
}

// Round 2
// 420.322 us; speedup vs baseline: 1.1784x; 1.1784x over previous
//
#include <hip/hip_runtime.h>

#define SEQ 550
#define MID 100
#define TPB 256

typedef _Float16 half2_t __attribute__((ext_vector_type(2)));

union H2I { int i; half2_t h; ushort2 u2; };

__device__ __forceinline__ float fdot2(half2_t a, half2_t b, float c) {
    return __builtin_amdgcn_fdot2(a, b, c, false);
}
__device__ __forceinline__ float sigm(float x) { return 1.0f / (1.0f + __expf(-x)); }
__device__ __forceinline__ float tanh_f(float x) { return 1.0f - 2.0f / (__expf(2.0f * x) + 1.0f); }
__device__ __forceinline__ half2_t i2h(int v) { H2I u; u.i = v; return u.h; }

// One row's gate projection: gh = w_hh[row].h + b_hh (fp32 acc), gi = w_ih[row].emb + b_ih
__device__ __forceinline__ void row_proj(const half2_t* __restrict__ whh2,
                                         const half2_t* __restrict__ wih2,
                                         float bih, float bhh,
                                         const half2_t* __restrict__ h,
                                         const half2_t* __restrict__ e,
                                         float& gi_out, float& gh_out) {
    float a0 = bhh, a1 = 0.0f, a2 = 0.0f, a3 = 0.0f;
    #pragma unroll
    for (int k = 0; k < 48; k += 4) {
        a0 = fdot2(whh2[k],     h[k],     a0);
        a1 = fdot2(whh2[k + 1], h[k + 1], a1);
        a2 = fdot2(whh2[k + 2], h[k + 2], a2);
        a3 = fdot2(whh2[k + 3], h[k + 3], a3);
    }
    a0 = fdot2(whh2[48], h[48], a0);
    a1 = fdot2(whh2[49], h[49], a1);
    gh_out = (a0 + a1) + (a2 + a3);

    float gi = bih;
    gi = fdot2(wih2[0], e[0], gi);
    gi = fdot2(wih2[1], e[1], gi);
    gi = fdot2(wih2[2], e[2], gi);
    gi = fdot2(wih2[3], e[3], gi);
    gi = fdot2(wih2[4], e[4], gi);
    gi_out = gi;
}

__global__ __launch_bounds__(TPB, 1) void gru_fused(
    const int*   __restrict__ x,
    const float* __restrict__ hidden,
    const float* __restrict__ embed,
    const float* __restrict__ w_ih,
    const float* __restrict__ w_hh,
    const float* __restrict__ b_ih,
    const float* __restrict__ b_hh,
    const float* __restrict__ fc_w,
    const float* __restrict__ fc_b,
    float*       __restrict__ out)
{
    // LDS
    __shared__ __align__(16) ushort seq16[SEQ * 16];   // emb as fp16, 32B stride/t: 17.6 KB
    __shared__ float gates[MID * 5];                   // per-unit {a_r, a_z, g_in, g_hn, pad}, stride 5 dwords
    __shared__ __align__(16) int h2buf[52];            // h as 50 packed half2 dwords + pad
    __shared__ float partial[MID];

    const int tid  = threadIdx.x;
    const int lane = tid & 63;

    // ---- stage embedded sequence as fp16 ----
    for (int i = tid; i < SEQ * 10; i += TPB) {
        int t = i / 10;
        int k = i - 10 * t;
        H2I u; u.h = half2_t{(_Float16)embed[x[t] * 10 + k], (_Float16)0.0f};
        seq16[t * 16 + k] = u.u2.x;
    }

    // ---- row assignment ----
    // row0 = tid (rows 0..255).  row1 = tid+192 for tid in [64,108) (rows 256..299).
    const int  row0 = tid;
    const int  g0   = tid / 100;            // 0,1,2
    const int  j0   = tid - g0 * 100;
    const bool has2 = (tid >= 64 && tid < 108);
    const int  j1   = tid - 8;              // (tid+192) - 200, g=2 always

    // ---- per-thread weights in registers (fp16 pairs) ----
    half2_t whh2a[50], whh2b[50];
    half2_t wih2a[5],  wih2b[5];
    float biha = 0.f, bhha = 0.f, bihb = 0.f, bhhb = 0.f;
    {
        const float4* wr = (const float4*)(w_hh + row0 * MID);
        #pragma unroll
        for (int k = 0; k < 25; k++) {
            float4 f = wr[k];
            whh2a[2 * k]     = half2_t{(_Float16)f.x, (_Float16)f.y};
            whh2a[2 * k + 1] = half2_t{(_Float16)f.z, (_Float16)f.w};
        }
        #pragma unroll
        for (int k = 0; k < 5; k++)
            wih2a[k] = half2_t{(_Float16)w_ih[row0 * 10 + 2 * k],
                               (_Float16)w_ih[row0 * 10 + 2 * k + 1]};
        biha = b_ih[row0];
        bhha = b_hh[row0];
    }
    if (has2) {
        const int row1 = tid + 192;
        const float4* wr = (const float4*)(w_hh + row1 * MID);
        #pragma unroll
        for (int k = 0; k < 25; k++) {
            float4 f = wr[k];
            whh2b[2 * k]     = half2_t{(_Float16)f.x, (_Float16)f.y};
            whh2b[2 * k + 1] = half2_t{(_Float16)f.z, (_Float16)f.w};
        }
        #pragma unroll
        for (int k = 0; k < 5; k++)
            wih2b[k] = half2_t{(_Float16)w_ih[row1 * 10 + 2 * k],
                               (_Float16)w_ih[row1 * 10 + 2 * k + 1]};
        bihb = b_ih[row1];
        bhhb = b_hh[row1];
    }

    // ---- phase-2 ownership: tid in [128,228) owns hidden unit u = tid-128 ----
    const bool owns_h = (tid >= 128 && tid < 228);
    const int  u      = tid - 128;
    float hreg = 0.0f, fcw = 0.0f;
    if (owns_h) {
        hreg = hidden[u];
        ((_Float16*)h2buf)[u] = (_Float16)hreg;
        fcw = fc_w[u];
    }
    float fcb = (tid == 0) ? fc_b[0] : 0.0f;

    __syncthreads();

    #pragma unroll 1
    for (int t = 0; t < SEQ; t++) {
        // ---- broadcast h: 13 lanes load 16B each, then readlane -> wave-uniform ----
        int4 hv = ((const int4*)h2buf)[lane < 13 ? lane : 12];
        half2_t h[50];
        #pragma unroll
        for (int k = 0; k < 50; k++) {
            int comp = k & 3;
            int src  = (comp == 0) ? hv.x : (comp == 1) ? hv.y : (comp == 2) ? hv.z : hv.w;
            h[k] = i2h(__builtin_amdgcn_readlane(src, k >> 2));
        }

        // ---- broadcast emb_t (10 halves, same-address reads) ----
        int4 e4 = ((const int4*)seq16)[t * 2];
        int  e1 = ((const int*)seq16)[t * 8 + 4];
        half2_t e[5] = {i2h(e4.x), i2h(e4.y), i2h(e4.z), i2h(e4.w), i2h(e1)};

        // ---- phase 1: gate projections ----
        float gi0, gh0;
        row_proj(whh2a, wih2a, biha, bhha, h, e, gi0, gh0);
        if (g0 == 2) {
            gates[j0 * 5 + 2] = gi0;
            gates[j0 * 5 + 3] = gh0;
        } else {
            gates[j0 * 5 + g0] = gi0 + gh0;
        }
        if (has2) {
            float gi1, gh1;
            row_proj(whh2b, wih2b, bihb, bhhb, h, e, gi1, gh1);
            gates[j1 * 5 + 2] = gi1;
            gates[j1 * 5 + 3] = gh1;
        }
        __syncthreads();

        // ---- phase 2: gate mixing + h update (waves 2,3) ----
        if (owns_h) {
            float ar  = gates[u * 5 + 0];
            float az  = gates[u * 5 + 1];
            float gin = gates[u * 5 + 2];
            float ghn = gates[u * 5 + 3];
            float r = sigm(ar);
            float z = sigm(az);
            float n = tanh_f(gin + r * ghn);
            hreg = n + z * (hreg - n);          // (1-z)*n + z*h, exact fp32 state
            ((_Float16*)h2buf)[u] = (_Float16)hreg;
        }
        __syncthreads();
    }

    // ---- epilogue: sigmoid(relu(h) . fc_w + fc_b) ----
    if (owns_h) partial[u] = fmaxf(hreg, 0.0f) * fcw;
    __syncthreads();
    if (tid == 0) {
        float s = fcb;
        #pragma unroll 1
        for (int k = 0; k < MID; k++) s += partial[k];
        out[0] = sigm(s);
    }
}

extern "C" void kernel_launch(void* const* d_in, const int* in_sizes, int n_in,
                              void* d_out, int out_size, void* d_ws, size_t ws_size,
                              hipStream_t stream) {
    const int*   x      = (const int*)  d_in[0];
    const float* hidden = (const float*)d_in[1];
    const float* embed  = (const float*)d_in[2];
    const float* w_ih   = (const float*)d_in[3];
    const float* w_hh   = (const float*)d_in[4];
    const float* b_ih   = (const float*)d_in[5];
    const float* b_hh   = (const float*)d_in[6];
    const float* fc_w   = (const float*)d_in[7];
    const float* fc_b   = (const float*)d_in[8];
    float*       out    = (float*)d_out;

    gru_fused<<<1, TPB, 0, stream>>>(x, hidden, embed, w_ih, w_hh,
                                     b_ih, b_hh, fc_w, fc_b, out);
}